// Round 9
// baseline (655.397 us; speedup 1.0000x reference)
//
#include <hip/hip_runtime.h>
#include <hip/hip_bf16.h>

typedef _Float16 half8 __attribute__((ext_vector_type(8)));
typedef float floatx4 __attribute__((ext_vector_type(4)));

#define NEDGE 200000
#define ETOT  400000
#define BM 64
#define NTILES (ETOT / BM)   /* 6250 exact */
#define NBLOCKS 256

__device__ _Float16 g_w1[256 * 256];       // [n][k] fp16 (transposed W1)
__device__ _Float16 g_w2[256 * 256];       // [n][k] fp16 (transposed W2)
__device__ _Float16 g_xh[100000L * 256];   // fp16 x (51.2 MB)
__device__ _Float16 g_e[(long)ETOT * 256]; // fp16 e = x[s]*x[d] (204.8 MB)

__global__ void prep_weights(const float* __restrict__ W1, const float* __restrict__ W2) {
    int t = blockIdx.x * 256 + threadIdx.x;   // t = k*256 + n
    int k = t >> 8, n = t & 255;
    g_w1[n * 256 + k] = (_Float16)W1[t];
    g_w2[n * 256 + k] = (_Float16)W2[t];
}

__global__ void prep_x(const float* __restrict__ x) {
    long i = ((long)blockIdx.x * 256 + threadIdx.x) * 8;  // 12500 blocks exact
    floatx4 v0 = *(const floatx4*)(x + i);
    floatx4 v1 = *(const floatx4*)(x + i + 4);
    half8 h;
    h[0] = (_Float16)v0[0]; h[1] = (_Float16)v0[1];
    h[2] = (_Float16)v0[2]; h[3] = (_Float16)v0[3];
    h[4] = (_Float16)v1[0]; h[5] = (_Float16)v1[1];
    h[6] = (_Float16)v1[2]; h[7] = (_Float16)v1[3];
    *(half8*)(g_xh + i) = h;
}

// ---- K2: pure gather + product, max occupancy, no LDS/barriers (proven ~65us) ----
__global__ __launch_bounds__(256) void gather_product(
    const int* __restrict__ psrc, const int* __restrict__ pdst,
    const int* __restrict__ nsrc, const int* __restrict__ ndst)
{
    int gid = blockIdx.x * 256 + threadIdx.x;
    int e = gid >> 5;
    int c = (gid & 31) * 8;
    int s, d;
    if (e < NEDGE) { s = psrc[e]; d = pdst[e]; }
    else           { s = nsrc[e - NEDGE]; d = ndst[e - NEDGE]; }
    half8 a = *(const half8*)(g_xh + (long)s * 256 + c);
    half8 b = *(const half8*)(g_xh + (long)d * 256 + c);
    *(half8*)(g_e + (long)e * 256 + c) = a * b;
}

// async global->LDS, 16B/lane; LDS dest = wave-uniform base + lane*16
#define GLOAD_LDS16(g, l) \
    __builtin_amdgcn_global_load_lds((const __attribute__((address_space(1))) unsigned int*)(g), \
                                     (__attribute__((address_space(3))) unsigned int*)(l), 16, 0, 0)

// LDS-publish barrier (lgkm only; vmcnt handled separately)
__device__ __forceinline__ void bar_lds() {
    __builtin_amdgcn_sched_barrier(0);
    asm volatile("s_waitcnt lgkmcnt(0)" ::: "memory");
    __builtin_amdgcn_s_barrier();
    __builtin_amdgcn_sched_barrier(0);
}

// ---- K3: persistent-block MLP, double-buffered e-tiles, W1 in registers ----
// 8 waves = 2M x 4N over a 64x256 tile; per wave 32 rows x 64 cols.
__global__ __launch_bounds__(512, 2) void mlp(
    const float* __restrict__ b1, const float* __restrict__ b2,
    const float* __restrict__ W3, const float* __restrict__ b3,
    float* __restrict__ out)
{
    __shared__ _Float16 eT[2][BM * 256];  // 2 x 32KB, rows XOR-swizzled
    __shared__ _Float16 h1T[BM * 256];    // 32KB
    __shared__ float part[BM * 4];        // 1KB

    const int tid  = threadIdx.x;
    const int lane = tid & 63;
    const int wid  = tid >> 6;     // 0..7
    const int l15  = lane & 15;
    const int lhi  = lane >> 4;
    const int mr   = wid >> 2;     // 0..1: row half [mr*32, +32)
    const int nc   = wid & 3;      // 0..3: col quarter
    const int n0   = nc * 64;

    // ---- persistent W1 slice in registers (128 VGPRs) ----
    half8 w1r[4][8];
    {
        const _Float16* __restrict__ wb1 = g_w1 + (n0 + l15) * 256 + lhi * 8;
        #pragma unroll
        for (int ni = 0; ni < 4; ++ni)
            #pragma unroll
            for (int kk = 0; kk < 8; ++kk)
                w1r[ni][kk] = *(const half8*)(wb1 + ni * 4096 + kk * 32);
    }
    float b1v[4], b2v[4], w3v[4];
    #pragma unroll
    for (int ni = 0; ni < 4; ++ni) {
        b1v[ni] = b1[n0 + ni * 16 + l15];
        b2v[ni] = b2[n0 + ni * 16 + l15];
        w3v[ni] = W3[n0 + ni * 16 + l15];
    }
    const float b3v = b3[0];

    const unsigned aswz  = (unsigned)((l15 & 7) << 4);
    const unsigned abase = (unsigned)((mr * 32 + l15) * 512 + lhi * 16);
    const _Float16* __restrict__ wb2 = g_w2 + (n0 + l15) * 256 + lhi * 8;

    // stage one 32KB e-tile: 4 rounds x (wave covers 2 rows = 1KB per gload)
    const int ch = lane & 31;
    auto stage = [&](_Float16* dst, int t) {
        const _Float16* __restrict__ tb = g_e + (long)t * (BM * 256);
        #pragma unroll
        for (int r = 0; r < 4; ++r) {
            const int r2  = r * 16 + wid * 2;
            const int row = r2 + (lane >> 5);
            const char* g = (const char*)(tb + (long)row * 256) + ((ch ^ (row & 7)) * 16);
            GLOAD_LDS16(g, (char*)dst + r2 * 512);
        }
    };

    // ---- prologue ----
    int t = blockIdx.x;
    stage(eT[0], t);
    asm volatile("s_waitcnt vmcnt(0)" ::: "memory");
    __syncthreads();

    int cur = 0;
    for (; t < NTILES; t += NBLOCKS) {
        const int tn = t + NBLOCKS;
        if (tn < NTILES) stage(eT[cur ^ 1], tn);   // async prefetch for t+1

        // preload W2 kk=0 fragments early (consumed ~3K cycles later)
        half8 bcur[4], bnext[4];
        #pragma unroll
        for (int ni = 0; ni < 4; ++ni) bcur[ni] = *(const half8*)(wb2 + ni * 4096);

        // ---- layer 1: A from eT[cur] (LDS), B = w1r (registers) ----
        floatx4 acc[2][4];
        #pragma unroll
        for (int mi = 0; mi < 2; ++mi)
            #pragma unroll
            for (int ni = 0; ni < 4; ++ni)
                acc[mi][ni] = (floatx4){0.f, 0.f, 0.f, 0.f};
        #pragma unroll
        for (int kk = 0; kk < 8; ++kk) {
            half8 a0 = *(const half8*)((char*)eT[cur] + ((abase + kk * 64) ^ aswz));
            half8 a1 = *(const half8*)((char*)eT[cur] + ((abase + 8192 + kk * 64) ^ aswz));
            #pragma unroll
            for (int ni = 0; ni < 4; ++ni) {
                acc[0][ni] = __builtin_amdgcn_mfma_f32_16x16x32_f16(a0, w1r[ni][kk], acc[0][ni], 0, 0, 0);
                acc[1][ni] = __builtin_amdgcn_mfma_f32_16x16x32_f16(a1, w1r[ni][kk], acc[1][ni], 0, 0, 0);
            }
        }

        // h1 bias+relu -> h1T (own exclusive 32x64 region, same swizzle)
        #pragma unroll
        for (int mi = 0; mi < 2; ++mi)
            #pragma unroll
            for (int ni = 0; ni < 4; ++ni)
                #pragma unroll
                for (int r = 0; r < 4; ++r) {
                    float h = fmaxf(acc[mi][ni][r] + b1v[ni], 0.f);
                    int row = mr * 32 + mi * 16 + lhi * 4 + r;
                    int col = n0 + ni * 16 + l15;
                    unsigned addr = ((unsigned)(row * 512 + col * 2)) ^ ((unsigned)((row & 7) << 4));
                    *(_Float16*)((char*)h1T + addr) = (_Float16)h;
                }
        bar_lds();   // BAR1: h1 published

        // ---- layer 2: A from h1T, B = W2 streamed (rolling prefetch) ----
        #pragma unroll
        for (int mi = 0; mi < 2; ++mi)
            #pragma unroll
            for (int ni = 0; ni < 4; ++ni)
                acc[mi][ni] = (floatx4){0.f, 0.f, 0.f, 0.f};
        #pragma unroll
        for (int kk = 0; kk < 8; ++kk) {
            if (kk < 7) {
                #pragma unroll
                for (int ni = 0; ni < 4; ++ni)
                    bnext[ni] = *(const half8*)(wb2 + ni * 4096 + (kk + 1) * 32);
            }
            half8 a0 = *(const half8*)((char*)h1T + ((abase + kk * 64) ^ aswz));
            half8 a1 = *(const half8*)((char*)h1T + ((abase + 8192 + kk * 64) ^ aswz));
            #pragma unroll
            for (int ni = 0; ni < 4; ++ni) {
                acc[0][ni] = __builtin_amdgcn_mfma_f32_16x16x32_f16(a0, bcur[ni], acc[0][ni], 0, 0, 0);
                acc[1][ni] = __builtin_amdgcn_mfma_f32_16x16x32_f16(a1, bcur[ni], acc[1][ni], 0, 0, 0);
            }
            #pragma unroll
            for (int ni = 0; ni < 4; ++ni) bcur[ni] = bnext[ni];
        }

        // ---- layer 3 partials ----
        #pragma unroll
        for (int mi = 0; mi < 2; ++mi)
            #pragma unroll
            for (int r = 0; r < 4; ++r) {
                float s = 0.f;
                #pragma unroll
                for (int ni = 0; ni < 4; ++ni)
                    s += fmaxf(acc[mi][ni][r] + b2v[ni], 0.f) * w3v[ni];
                s += __shfl_xor(s, 1);
                s += __shfl_xor(s, 2);
                s += __shfl_xor(s, 4);
                s += __shfl_xor(s, 8);
                if (l15 == 0)
                    part[(mr * 32 + mi * 16 + lhi * 4 + r) * 4 + nc] = s;
            }

        // prefetched gathers (issued ~4K cycles ago) must land before publish
        asm volatile("s_waitcnt vmcnt(0)" ::: "memory");
        bar_lds();   // BAR2: eT[cur^1] + part published

        // ---- output store: wave w rows [w*8, +8) ----
        if (lane < 8) {
            int row = wid * 8 + lane;
            const float* p = part + row * 4;
            out[t * BM + row] = p[0] + p[1] + p[2] + p[3] + b3v;
        }
        cur ^= 1;
    }
}

extern "C" void kernel_launch(void* const* d_in, const int* in_sizes, int n_in,
                              void* d_out, int out_size, void* d_ws, size_t ws_size,
                              hipStream_t stream) {
    const float* x    = (const float*)d_in[0];
    const int* psrc   = (const int*)d_in[1];
    const int* pdst   = (const int*)d_in[2];
    const int* nsrc   = (const int*)d_in[3];
    const int* ndst   = (const int*)d_in[4];
    const float* W1   = (const float*)d_in[5];
    const float* b1   = (const float*)d_in[6];
    const float* W2   = (const float*)d_in[7];
    const float* b2   = (const float*)d_in[8];
    const float* W3   = (const float*)d_in[9];
    const float* b3   = (const float*)d_in[10];

    prep_weights<<<256, 256, 0, stream>>>(W1, W2);
    prep_x<<<12500, 256, 0, stream>>>(x);
    gather_product<<<ETOT / 8, 256, 0, stream>>>(psrc, pdst, nsrc, ndst);
    mlp<<<NBLOCKS, 512, 0, stream>>>(b1, b2, W3, b3, (float*)d_out);
}